// Round 8
// baseline (532.859 us; speedup 1.0000x reference)
//
#include <hip/hip_runtime.h>

// ---------------- problem constants ----------------
constexpr int NPEP = 20000, NMHC = 5000, NTCR = 100000;
constexpr int EPM = 200000, EMT = 400000, BB = 50000;

typedef __attribute__((ext_vector_type(8))) short bf16x8;
typedef __attribute__((ext_vector_type(4))) float f32x4;

__device__ inline ushort f2bf(float x) {
    union { float f; unsigned u; } v; v.f = x;
    unsigned r = (v.u + 0x7FFF + ((v.u >> 16) & 1)) >> 16;
    return (ushort)r;
}
__device__ inline float bf2f(ushort b) {
    union { unsigned u; float f; } t; t.u = ((unsigned)b) << 16; return t.f;
}
__device__ inline void bf2x2(unsigned u, float& a, float& b) {
    union { unsigned x; float f; } t1, t2;
    t1.x = u << 16; t2.x = u & 0xffff0000u;
    a = t1.f; b = t2.f;
}
__device__ inline ushort4 f4bf(float4 v) {
    return make_ushort4(f2bf(v.x), f2bf(v.y), f2bf(v.z), f2bf(v.w));
}

// ---------------- merged prep kernel (block-range dispatch) ----------------
__global__ __launch_bounds__(256) void prep_kernel(
    int* __restrict__ ibz,
    const float4* __restrict__ emb_tcr, ushort4* __restrict__ emb_tcr_b,
    const float4* __restrict__ emb_pep, ushort4* __restrict__ emb_pep_b,
    const float4* __restrict__ Wr1f, ushort4* __restrict__ Wr1_b,
    const float4* __restrict__ Wr2f, ushort4* __restrict__ Wr2_b,
    const float* __restrict__ head_W1, ushort4* __restrict__ W1b_b, ushort4* __restrict__ W1c_b,
    const float* __restrict__ l1_pm_Wl, const float* __restrict__ l1_pm_Wr,
    const float* __restrict__ l1_mt_Wl, ushort* __restrict__ Wcat1_b,
    const float* __restrict__ l2_pm_Wl, const float* __restrict__ l2_pm_Wr,
    const float* __restrict__ l2_mt_Wl, ushort* __restrict__ Wcat2_b,
    const float4* __restrict__ emb_mhc, ushort* __restrict__ Acat1,
    const float* __restrict__ proj_W, const float* __restrict__ proj_b,
    ushort* __restrict__ Wcomp_b, float* __restrict__ bp) {
    __shared__ float red[128];
    const int b = blockIdx.x, tid = threadIdx.x;
    if (b < 206) {
        int i = b * 256 + tid;
        if (i < 52500) ((int4*)ibz)[i] = make_int4(0, 0, 0, 0);
    } else if (b < 12706) {
        int i = (b - 206) * 256 + tid;
        if (i < 3200000) emb_tcr_b[i] = f4bf(emb_tcr[i]);
    } else if (b < 15206) {
        int i = (b - 12706) * 256 + tid;
        if (i < 640000) emb_pep_b[i] = f4bf(emb_pep[i]);
    } else if (b < 15238) {
        int i = (b - 15206) * 256 + tid;
        if (i < 8192) Wr1_b[i] = f4bf(Wr1f[i]);
    } else if (b < 15302) {
        int i = (b - 15238) * 256 + tid;
        if (i < 16384) Wr2_b[i] = f4bf(Wr2f[i]);
    } else if (b < 15366) {
        int i = (b - 15302) * 256 + tid;
        if (i < 16384) {
            int n = i >> 6, k4 = (i & 63) * 4;
            float4 v = *(const float4*)(head_W1 + (size_t)n * 768 + 256 + k4);
            W1b_b[i] = f4bf(v);
        }
    } else if (b < 15430) {
        int i = (b - 15366) * 256 + tid;
        if (i < 16384) {
            int n = i >> 6, k4 = (i & 63) * 4;
            float4 v = *(const float4*)(head_W1 + (size_t)n * 768 + 512 + k4);
            W1c_b[i] = f4bf(v);
        }
    } else if (b < 15942) {
        int idx = (b - 15430) * 256 + tid;   // 512x256
        if (idx < 131072) {
            int r = idx >> 8, k = idx & 255;
            float v;
            if (r < 256) v = (k < 128) ? l1_pm_Wl[r * 128 + k] : l1_pm_Wr[r * 128 + (k - 128)];
            else         v = (k < 128) ? 0.f : l1_mt_Wl[(r - 256) * 128 + (k - 128)];
            Wcat1_b[idx] = f2bf(v);
        }
    } else if (b < 16710) {
        int idx = (b - 15942) * 256 + tid;   // 512x384
        if (idx < 196608) {
            int r = idx / 384, k = idx - r * 384;
            float v;
            if (r < 256) v = (k < 128) ? l2_pm_Wl[r * 128 + k] : l2_pm_Wr[r * 256 + (k - 128)];
            else         v = (k < 128) ? 0.f : l2_mt_Wl[(r - 256) * 256 + (k - 128)];
            Wcat2_b[idx] = f2bf(v);
        }
    } else if (b < 17335) {
        int i4 = (b - 16710) * 256 + tid;
        if (i4 < 160000) {
            int r = i4 >> 5, c4 = (i4 & 31) * 4;
            *(ushort4*)(Acat1 + (size_t)r * 256 + 128 + c4) = f4bf(emb_mhc[i4]);
        }
    } else {
        // wcomp: one block per output row i (0..255)
        int i = b - 17335;
        const float* w1row = head_W1 + (size_t)i * 768;
        if (tid < 128) {
            float acc = 0.f;
            for (int k = 0; k < 256; k++) acc += w1row[k] * proj_W[k * 128 + tid];
            Wcomp_b[i * 128 + tid] = f2bf(acc);
            float pb = w1row[2 * tid] * proj_b[2 * tid] + w1row[2 * tid + 1] * proj_b[2 * tid + 1];
            red[tid] = pb;
        }
        __syncthreads();
        if (tid < 64) { red[tid] += red[tid + 64]; }
        __syncthreads();
        if (tid < 32) { red[tid] += red[tid + 32]; }
        __syncthreads();
        if (tid == 0) {
            float s = 0.f;
            for (int j = 0; j < 32; j++) s += red[j];
            bp[i] = s;
        }
    }
}

// ---------------- merged histogram ----------------
__global__ void hist2_kernel(const int* __restrict__ dst_pm, const int* __restrict__ dst_mt,
                             int* __restrict__ deg_pm, int* __restrict__ deg_mt) {
    int t = blockIdx.x * blockDim.x + threadIdx.x;
    if (t < EPM) atomicAdd(&deg_pm[dst_pm[t]], 1);
    else if (t < EPM + EMT) atomicAdd(&deg_mt[dst_mt[t - EPM]], 1);
}

// ---------------- merged blocksum ----------------
__global__ __launch_bounds__(256) void blocksum2_kernel(const int* __restrict__ deg_pm,
                                                        const int* __restrict__ deg_mt,
                                                        int* __restrict__ bsum_pm,
                                                        int* __restrict__ bsum_mt) {
    __shared__ int red[256];
    const int tid = threadIdx.x;
    const int* deg; int n, bi; int* bsum;
    if (blockIdx.x < 5) { deg = deg_pm; n = NMHC; bi = blockIdx.x; bsum = bsum_pm; }
    else { deg = deg_mt; n = NTCR; bi = blockIdx.x - 5; bsum = bsum_mt; }
    const int base = bi * 1024;
    int s = 0;
#pragma unroll
    for (int j = 0; j < 4; j++) {
        int i = base + tid + j * 256;
        if (i < n) s += deg[i];
    }
    red[tid] = s;
    __syncthreads();
    for (int off = 128; off > 0; off >>= 1) {
        if (tid < off) red[tid] += red[tid + off];
        __syncthreads();
    }
    if (tid == 0) bsum[bi] = red[0];
}

// ---------------- merged scan of block sums ----------------
__global__ __launch_bounds__(128) void scanb2_kernel(int* __restrict__ bsum_pm,
                                                     int* __restrict__ bsum_mt) {
    __shared__ int s[128];
    const int tid = threadIdx.x;
    int* bsum = (blockIdx.x == 0) ? bsum_pm : bsum_mt;
    const int nb = (blockIdx.x == 0) ? 5 : 98;
    int v = (tid < nb) ? bsum[tid] : 0;
    s[tid] = v;
    __syncthreads();
    for (int off = 1; off < 128; off <<= 1) {
        int t = (tid >= off) ? s[tid - off] : 0;
        __syncthreads();
        s[tid] += t;
        __syncthreads();
    }
    if (tid < nb) bsum[tid] = (tid > 0) ? s[tid - 1] : 0;
    if (tid == 0) bsum[nb] = s[nb - 1];
}

// ---------------- merged emit ----------------
__global__ __launch_bounds__(256) void emit2_kernel(const int* __restrict__ deg_pm,
                                                    const int* __restrict__ deg_mt,
                                                    const int* __restrict__ bsum_pm,
                                                    const int* __restrict__ bsum_mt,
                                                    int* __restrict__ rp_pm, float* __restrict__ cnt_pm,
                                                    int* __restrict__ rp_mt, float* __restrict__ cnt_mt) {
    __shared__ int tsum[256];
    const int tid = threadIdx.x;
    const int* deg; const int* bsum; int* rp; float* cnt; int n, nb, bi;
    if (blockIdx.x < 5) { deg = deg_pm; bsum = bsum_pm; rp = rp_pm; cnt = cnt_pm; n = NMHC; nb = 5; bi = blockIdx.x; }
    else { deg = deg_mt; bsum = bsum_mt; rp = rp_mt; cnt = cnt_mt; n = NTCR; nb = 98; bi = blockIdx.x - 5; }
    const int i0 = bi * 1024 + tid * 4;
    int4 v = make_int4(0, 0, 0, 0);
    if (i0 + 3 < n) v = *(const int4*)(deg + i0);
    else if (i0 < n) {
        int t[4] = {0, 0, 0, 0};
        for (int j = 0; j < 4 && i0 + j < n; j++) t[j] = deg[i0 + j];
        v = make_int4(t[0], t[1], t[2], t[3]);
    }
    int s = v.x + v.y + v.z + v.w;
    tsum[tid] = s;
    __syncthreads();
    for (int off = 1; off < 256; off <<= 1) {
        int t = (tid >= off) ? tsum[tid - off] : 0;
        __syncthreads();
        tsum[tid] += t;
        __syncthreads();
    }
    int ex = ((tid > 0) ? tsum[tid - 1] : 0) + bsum[bi];
    if (i0 + 3 < n) {
        int r1 = ex + v.x, r2 = r1 + v.y, r3 = r2 + v.z;
        *(int4*)(rp + i0) = make_int4(ex, r1, r2, r3);
        *(float4*)(cnt + i0) = make_float4((float)v.x, (float)v.y, (float)v.z, (float)v.w);
    } else if (i0 < n) {
        int r = ex;
        int vv[4] = {v.x, v.y, v.z, v.w};
        for (int j = 0; j < 4 && i0 + j < n; j++) {
            rp[i0 + j] = r;
            cnt[i0 + j] = (float)vv[j];
            r += vv[j];
        }
    }
    if (bi == 0 && tid == 0) rp[n] = bsum[nb];
}

// ---------------- merged CSR fill ----------------
__global__ void fill2_kernel(const int* __restrict__ src_pm, const int* __restrict__ dst_pm,
                             const int* __restrict__ src_mt, const int* __restrict__ dst_mt,
                             const int* __restrict__ rp_pm, int* __restrict__ cur_pm, int* __restrict__ csr_pm,
                             const int* __restrict__ rp_mt, int* __restrict__ cur_mt, int* __restrict__ csr_mt) {
    int t = blockIdx.x * blockDim.x + threadIdx.x;
    if (t < EPM) {
        int d = dst_pm[t];
        int pos = atomicAdd(&cur_pm[d], 1);
        csr_pm[rp_pm[d] + pos] = src_pm[t];
    } else if (t < EPM + EMT) {
        int t2 = t - EPM;
        int d = dst_mt[t2];
        int pos = atomicAdd(&cur_mt[d], 1);
        csr_mt[rp_mt[d] + pos] = src_mt[t2];
    }
}

// ---------------- pm gather + mean -> bf16 ----------------
__global__ __launch_bounds__(256) void gatherpm_kernel(const int* __restrict__ rp,
                                                       const int* __restrict__ csr_src,
                                                       const float* __restrict__ X,
                                                       ushort* __restrict__ A1, ushort* __restrict__ A2,
                                                       int n) {
    const int tid = threadIdx.x;
    const int r = blockIdx.x * 8 + (tid >> 5);
    const int lane = tid & 31;
    if (r >= n) return;
    const int e0 = rp[r], e1 = rp[r + 1];
    float4 s = make_float4(0.f, 0.f, 0.f, 0.f);
    for (int e = e0; e < e1; e++) {
        const int sidx = csr_src[e];
        float4 v = ((const float4*)(X + (long)sidx * 128))[lane];
        s.x += v.x; s.y += v.y; s.z += v.z; s.w += v.w;
    }
    float sc = 1.f / fmaxf((float)(e1 - e0), 1.f);
    ushort4 o = make_ushort4(f2bf(s.x * sc), f2bf(s.y * sc), f2bf(s.z * sc), f2bf(s.w * sc));
    *(ushort4*)(A1 + (size_t)r * 256 + lane * 4) = o;
    *(ushort4*)(A2 + (size_t)r * 384 + lane * 4) = o;
}

// ---------------- bf16 pull gather (mt relation) ----------------
__global__ __launch_bounds__(256) void gatherb_kernel(const int* __restrict__ rp,
                                                      const int* __restrict__ csr_src,
                                                      const ushort* __restrict__ Zb,
                                                      ushort* __restrict__ accb, int n) {
    const int tid = threadIdx.x;
    const int r = blockIdx.x * 8 + (tid >> 5);
    const int lane = tid & 31;
    if (r >= n) return;
    const int e0 = rp[r], e1 = rp[r + 1];
    float s[8] = {};
    for (int e = e0; e < e1; e++) {
        const int sidx = csr_src[e];
        uint4 u = *(const uint4*)(Zb + (size_t)sidx * 256 + lane * 8);
        float a, b;
        bf2x2(u.x, a, b); s[0] += a; s[1] += b;
        bf2x2(u.y, a, b); s[2] += a; s[3] += b;
        bf2x2(u.z, a, b); s[4] += a; s[5] += b;
        bf2x2(u.w, a, b); s[6] += a; s[7] += b;
    }
    ushort o[8];
#pragma unroll
    for (int j = 0; j < 8; j++) o[j] = f2bf(s[j]);
    uint4 w;
    w.x = (unsigned)o[0] | ((unsigned)o[1] << 16);
    w.y = (unsigned)o[2] | ((unsigned)o[3] << 16);
    w.z = (unsigned)o[4] | ((unsigned)o[5] << 16);
    w.w = (unsigned)o[6] | ((unsigned)o[7] << 16);
    *(uint4*)(accb + (size_t)r * 256 + lane * 8) = w;
}

// ---------------- bf16 MFMA fused GEMM (layer1/layer2): dual bf16 outputs ----------------
template <int K, int NB0, bool RELU0, bool G2>
__global__ __launch_bounds__(256, 2) void mfma_fused_kernel(
    int M, const ushort* __restrict__ A, const ushort* __restrict__ W,
    const float* __restrict__ bias,
    ushort* __restrict__ out0, int s0, ushort* __restrict__ out1) {
    constexpr int RS = 40;
    __shared__ ushort Als[128 * RS];
    __shared__ ushort Wls[128 * RS];
    const int tid = threadIdx.x;
    const int m0 = blockIdx.x * 128, n0 = blockIdx.y * 128;
    const int lane = tid & 63, w = tid >> 6;
    const int wm = w >> 1, wn = w & 1;
    const int m16 = lane & 15, q = lane >> 4;

    f32x4 acc[4][4] = {};

    for (int k0 = 0; k0 < K; k0 += 32) {
        bf16x8 a_st[2], w_st[2];
#pragma unroll
        for (int r = 0; r < 2; r++) {
            int chunk = tid + r * 256;
            int row = chunk >> 2, off = (chunk & 3) * 8;
            int ga = min(m0 + row, M - 1);
            a_st[r] = *(const bf16x8*)(A + (size_t)ga * K + k0 + off);
            w_st[r] = *(const bf16x8*)(W + (size_t)(n0 + row) * K + k0 + off);
        }
        __syncthreads();
#pragma unroll
        for (int r = 0; r < 2; r++) {
            int chunk = tid + r * 256;
            int row = chunk >> 2, off = (chunk & 3) * 8;
            *(bf16x8*)(&Als[row * RS + off]) = a_st[r];
            *(bf16x8*)(&Wls[row * RS + off]) = w_st[r];
        }
        __syncthreads();
        bf16x8 af[4], bf[4];
#pragma unroll
        for (int t = 0; t < 4; t++) {
            af[t] = *(const bf16x8*)(&Als[(wm * 64 + t * 16 + m16) * RS + q * 8]);
            bf[t] = *(const bf16x8*)(&Wls[(wn * 64 + t * 16 + m16) * RS + q * 8]);
        }
#pragma unroll
        for (int mt = 0; mt < 4; mt++)
#pragma unroll
            for (int nt = 0; nt < 4; nt++)
                acc[mt][nt] = __builtin_amdgcn_mfma_f32_16x16x32_bf16(af[mt], bf[nt], acc[mt][nt], 0, 0, 0);
    }

    const bool g1 = G2 && ((int)blockIdx.y >= NB0);
#pragma unroll
    for (int mt = 0; mt < 4; mt++) {
#pragma unroll
        for (int i = 0; i < 4; i++) {
            int row = m0 + wm * 64 + mt * 16 + q * 4 + i;
            if (row >= M) continue;
#pragma unroll
            for (int nt = 0; nt < 4; nt++) {
                int col = n0 + wn * 64 + nt * 16 + m16;
                float v = acc[mt][nt][i];
                if (!g1) {
                    v += bias[col];
                    if (RELU0) v = fmaxf(v, 0.f);
                    out0[(size_t)row * s0 + col] = f2bf(v);
                } else {
                    out1[(size_t)row * 256 + (col - NB0 * 128)] = f2bf(v);
                }
            }
        }
    }
}

// ---------------- mega tcr kernel: 3 chained MFMA stages through one LDS tile ----------------
// block = 64 rows x 256 cols; wave w owns cols [w*64, w*64+64)
// stage1: T = relu(emb@Wr1^T + bl1 + acc1/cnt)        (K=128)
// stage2: T = relu(T@Wr2^T + bl2 + acc2/cnt)          (K=256, in-place via barriers)
// stage3: Ht = T@W1c^T                                 (K=256, bf16 out)
__global__ __launch_bounds__(256) void tcr_mega_kernel(
    int M, const ushort* __restrict__ emb,
    const ushort* __restrict__ Wr1, const ushort* __restrict__ Wr2,
    const ushort* __restrict__ W1c,
    const float* __restrict__ bl1, const float* __restrict__ bl2,
    const float* __restrict__ cnt,
    const ushort* __restrict__ acc1, const ushort* __restrict__ acc2,
    ushort* __restrict__ Ht) {
    constexpr int RS2 = 264;               // 528B row stride -> 2-way max on b128 reads
    __shared__ ushort T[64 * RS2];
    const int tid = threadIdx.x;
    const int m0 = blockIdx.x * 64;
    const int lane = tid & 63, w = tid >> 6;
    const int m16 = lane & 15, q = lane >> 4;

    // ---- stage 1 ----
    {
        f32x4 a1[4][4] = {};
        for (int k0 = 0; k0 < 128; k0 += 32) {
            bf16x8 af[4], bf[4];
#pragma unroll
            for (int mt = 0; mt < 4; mt++) {
                int gr = min(m0 + mt * 16 + m16, M - 1);
                af[mt] = *(const bf16x8*)(emb + (size_t)gr * 128 + k0 + q * 8);
            }
#pragma unroll
            for (int nt = 0; nt < 4; nt++) {
                int n = w * 64 + nt * 16 + m16;
                bf[nt] = *(const bf16x8*)(Wr1 + (size_t)n * 128 + k0 + q * 8);
            }
#pragma unroll
            for (int mt = 0; mt < 4; mt++)
#pragma unroll
                for (int nt = 0; nt < 4; nt++)
                    a1[mt][nt] = __builtin_amdgcn_mfma_f32_16x16x32_bf16(af[mt], bf[nt], a1[mt][nt], 0, 0, 0);
        }
#pragma unroll
        for (int mt = 0; mt < 4; mt++)
#pragma unroll
            for (int i = 0; i < 4; i++) {
                int lr = mt * 16 + q * 4 + i;
                int rc = min(m0 + lr, M - 1);
                float es = 1.f / fmaxf(cnt[rc], 1.f);
#pragma unroll
                for (int nt = 0; nt < 4; nt++) {
                    int col = w * 64 + nt * 16 + m16;
                    float v = a1[mt][nt][i] + bl1[col] + bf2f(acc1[(size_t)rc * 256 + col]) * es;
                    T[lr * RS2 + col] = f2bf(fmaxf(v, 0.f));
                }
            }
    }
    __syncthreads();

    // ---- stage 2 (in-place) ----
    {
        f32x4 a2[4][4] = {};
        for (int k0 = 0; k0 < 256; k0 += 32) {
            bf16x8 af[4], bf[4];
#pragma unroll
            for (int mt = 0; mt < 4; mt++)
                af[mt] = *(const bf16x8*)(&T[(mt * 16 + m16) * RS2 + k0 + q * 8]);
#pragma unroll
            for (int nt = 0; nt < 4; nt++) {
                int n = w * 64 + nt * 16 + m16;
                bf[nt] = *(const bf16x8*)(Wr2 + (size_t)n * 256 + k0 + q * 8);
            }
#pragma unroll
            for (int mt = 0; mt < 4; mt++)
#pragma unroll
                for (int nt = 0; nt < 4; nt++)
                    a2[mt][nt] = __builtin_amdgcn_mfma_f32_16x16x32_bf16(af[mt], bf[nt], a2[mt][nt], 0, 0, 0);
        }
        __syncthreads();   // all waves done READING T before anyone overwrites
#pragma unroll
        for (int mt = 0; mt < 4; mt++)
#pragma unroll
            for (int i = 0; i < 4; i++) {
                int lr = mt * 16 + q * 4 + i;
                int rc = min(m0 + lr, M - 1);
                float es = 1.f / fmaxf(cnt[rc], 1.f);
#pragma unroll
                for (int nt = 0; nt < 4; nt++) {
                    int col = w * 64 + nt * 16 + m16;
                    float v = a2[mt][nt][i] + bl2[col] + bf2f(acc2[(size_t)rc * 256 + col]) * es;
                    T[lr * RS2 + col] = f2bf(fmaxf(v, 0.f));
                }
            }
    }
    __syncthreads();

    // ---- stage 3 ----
    {
        f32x4 a3[4][4] = {};
        for (int k0 = 0; k0 < 256; k0 += 32) {
            bf16x8 af[4], bf[4];
#pragma unroll
            for (int mt = 0; mt < 4; mt++)
                af[mt] = *(const bf16x8*)(&T[(mt * 16 + m16) * RS2 + k0 + q * 8]);
#pragma unroll
            for (int nt = 0; nt < 4; nt++) {
                int n = w * 64 + nt * 16 + m16;
                bf[nt] = *(const bf16x8*)(W1c + (size_t)n * 256 + k0 + q * 8);
            }
#pragma unroll
            for (int mt = 0; mt < 4; mt++)
#pragma unroll
                for (int nt = 0; nt < 4; nt++)
                    a3[mt][nt] = __builtin_amdgcn_mfma_f32_16x16x32_bf16(af[mt], bf[nt], a3[mt][nt], 0, 0, 0);
        }
#pragma unroll
        for (int mt = 0; mt < 4; mt++)
#pragma unroll
            for (int i = 0; i < 4; i++) {
                int row = m0 + mt * 16 + q * 4 + i;
                if (row >= M) continue;
#pragma unroll
                for (int nt = 0; nt < 4; nt++) {
                    int col = w * 64 + nt * 16 + m16;
                    Ht[(size_t)row * 256 + col] = f2bf(a3[mt][nt][i]);
                }
            }
    }
}

// ---------------- bf16 MFMA GEMM, bf16 output (Hp/Hm tables) ----------------
template <int K, bool HASB>
__global__ __launch_bounds__(256, 2) void mfma_out_kernel(
    int M, const ushort* __restrict__ A, const ushort* __restrict__ W,
    const float* __restrict__ bias, ushort* __restrict__ out) {
    constexpr int RS = 40;
    __shared__ ushort Als[128 * RS];
    __shared__ ushort Wls[128 * RS];
    const int tid = threadIdx.x;
    const int m0 = blockIdx.x * 128, n0 = blockIdx.y * 128;
    const int lane = tid & 63, w = tid >> 6;
    const int wm = w >> 1, wn = w & 1;
    const int m16 = lane & 15, q = lane >> 4;

    f32x4 acc[4][4] = {};

    for (int k0 = 0; k0 < K; k0 += 32) {
        bf16x8 a_st[2], w_st[2];
#pragma unroll
        for (int r = 0; r < 2; r++) {
            int chunk = tid + r * 256;
            int row = chunk >> 2, off = (chunk & 3) * 8;
            int ga = min(m0 + row, M - 1);
            a_st[r] = *(const bf16x8*)(A + (size_t)ga * K + k0 + off);
            w_st[r] = *(const bf16x8*)(W + (size_t)(n0 + row) * K + k0 + off);
        }
        __syncthreads();
#pragma unroll
        for (int r = 0; r < 2; r++) {
            int chunk = tid + r * 256;
            int row = chunk >> 2, off = (chunk & 3) * 8;
            *(bf16x8*)(&Als[row * RS + off]) = a_st[r];
            *(bf16x8*)(&Wls[row * RS + off]) = w_st[r];
        }
        __syncthreads();
        bf16x8 af[4], bf[4];
#pragma unroll
        for (int t = 0; t < 4; t++) {
            af[t] = *(const bf16x8*)(&Als[(wm * 64 + t * 16 + m16) * RS + q * 8]);
            bf[t] = *(const bf16x8*)(&Wls[(wn * 64 + t * 16 + m16) * RS + q * 8]);
        }
#pragma unroll
        for (int mt = 0; mt < 4; mt++)
#pragma unroll
            for (int nt = 0; nt < 4; nt++)
                acc[mt][nt] = __builtin_amdgcn_mfma_f32_16x16x32_bf16(af[mt], bf[nt], acc[mt][nt], 0, 0, 0);
    }

#pragma unroll
    for (int mt = 0; mt < 4; mt++) {
#pragma unroll
        for (int i = 0; i < 4; i++) {
            int row = m0 + wm * 64 + mt * 16 + q * 4 + i;
            if (row >= M) continue;
#pragma unroll
            for (int nt = 0; nt < 4; nt++) {
                int col = n0 + wn * 64 + nt * 16 + m16;
                float v = acc[mt][nt][i];
                if (HASB) v += bias[col];
                out[(size_t)row * 256 + col] = f2bf(v);
            }
        }
    }
}

// ---------------- combine: out[i] = relu(Hp[pp]+Hm[pm]+Ht[pt]+b1) . W2 + b2 ----------------
__global__ __launch_bounds__(256) void combine_kernel(
    const ushort* __restrict__ Hp, const ushort* __restrict__ Hm, const ushort* __restrict__ Ht,
    const int* __restrict__ pp, const int* __restrict__ pm, const int* __restrict__ pt,
    const float* __restrict__ b1, const float* __restrict__ W2, const float* __restrict__ b2,
    float* __restrict__ out) {
    const int tid = threadIdx.x;
    const int lane = tid & 63, w = tid >> 6;
    const int c = lane * 4;
    const float4 b1v = *(const float4*)(b1 + c);
    const float4 w2v = *(const float4*)(W2 + c);
    const float b2v = b2[0];
    const int base = blockIdx.x * 32 + w * 8;
#pragma unroll
    for (int t = 0; t < 8; t++) {
        int i = base + t;
        if (i >= BB) return;
        int ra = pp[i], rb = pm[i], rc = pt[i];
        ushort4 ua = *(const ushort4*)(Hp + (size_t)ra * 256 + c);
        ushort4 ub = *(const ushort4*)(Hm + (size_t)rb * 256 + c);
        ushort4 uc = *(const ushort4*)(Ht + (size_t)rc * 256 + c);
        float h0 = fmaxf(bf2f(ua.x) + bf2f(ub.x) + bf2f(uc.x) + b1v.x, 0.f);
        float h1 = fmaxf(bf2f(ua.y) + bf2f(ub.y) + bf2f(uc.y) + b1v.y, 0.f);
        float h2 = fmaxf(bf2f(ua.z) + bf2f(ub.z) + bf2f(uc.z) + b1v.z, 0.f);
        float h3 = fmaxf(bf2f(ua.w) + bf2f(ub.w) + bf2f(uc.w) + b1v.w, 0.f);
        float p = h0 * w2v.x + h1 * w2v.y + h2 * w2v.z + h3 * w2v.w;
#pragma unroll
        for (int off = 32; off > 0; off >>= 1) p += __shfl_down(p, off);
        if (lane == 0) out[i] = p + b2v;
    }
}

// ---------------- launch ----------------
extern "C" void kernel_launch(void* const* d_in, const int* in_sizes, int n_in,
                              void* d_out, int out_size, void* d_ws, size_t ws_size,
                              hipStream_t stream) {
    const float* emb_pep = (const float*)d_in[0];
    const float* emb_mhc = (const float*)d_in[1];
    const float* emb_tcr = (const float*)d_in[2];
    const int* src_pm = (const int*)d_in[3];
    const int* dst_pm = (const int*)d_in[4];
    const int* src_mt = (const int*)d_in[5];
    const int* dst_mt = (const int*)d_in[6];
    const int* pack_pep = (const int*)d_in[7];
    const int* pack_mhc = (const int*)d_in[8];
    const int* pack_tcr = (const int*)d_in[9];
    const float* l1_pm_Wl = (const float*)d_in[10];
    const float* l1_pm_bl = (const float*)d_in[11];
    const float* l1_pm_Wr = (const float*)d_in[12];
    const float* l1_mt_Wl = (const float*)d_in[13];
    const float* l1_mt_bl = (const float*)d_in[14];
    const float* l1_mt_Wr = (const float*)d_in[15];
    const float* l2_pm_Wl = (const float*)d_in[16];
    const float* l2_pm_bl = (const float*)d_in[17];
    const float* l2_pm_Wr = (const float*)d_in[18];
    const float* l2_mt_Wl = (const float*)d_in[19];
    const float* l2_mt_bl = (const float*)d_in[20];
    const float* l2_mt_Wr = (const float*)d_in[21];
    const float* proj_W = (const float*)d_in[22];
    const float* proj_b = (const float*)d_in[23];
    const float* head_W1 = (const float*)d_in[24];
    const float* head_b1 = (const float*)d_in[25];
    const float* head_W2 = (const float*)d_in[26];
    const float* head_b2 = (const float*)d_in[27];
    float* out = (float*)d_out;

    // ---------------- workspace layout ----------------
    int* ib = (int*)d_ws;
    int* deg_pm = ib;                 // 5000
    int* cur_pm = ib + 5000;          // 5000
    int* deg_mt = ib + 10000;         // 100000
    int* cur_mt = ib + 110000;        // 100000   [zero region: first 210000 ints]
    int* rp_pm  = ib + 210000;        // 5001 (pad 5008)
    int* rp_mt  = ib + 215008;        // 100001 (pad 100008)
    int* csr_pm = ib + 315016;        // 200000
    int* csr_mt = ib + 515016;        // 400000
    int* bsum_pm = ib + 915016;       // 160
    int* bsum_mt = ib + 915176;       // 160 -> pad 915344

    float* f = (float*)(ib + 915344);
    float* cnt_pm = f;                // 5000
    float* cnt_mt = f + 5000;         // 100000
    float* bp     = f + 105000;       // 256 (pad 105344)

    ushort* u = (ushort*)(f + 105344);
    ushort* Wcat1_b = u;              // 131072
    ushort* Wcat2_b = u + 131072;     // 196608
    ushort* W1b_b   = u + 327680;     // 65536
    ushort* W1c_b   = u + 393216;     // 65536
    ushort* Wcomp_b = u + 458752;     // 32768
    ushort* Wr1_b   = u + 491520;     // 32768
    ushort* Wr2_b   = u + 524288;     // 65536
    ushort* Acat1   = u + 589824;     // 1280000
    ushort* Acat2   = u + 1869824;    // 1920000
    ushort* Zb      = u + 3789824;    // 1280000
    ushort* mhc2_b  = u + 5069824;    // 1280000
    ushort* emb_pep_b = u + 6349824;  // 2560000
    ushort* Hp_b    = u + 8909824;    // 5120000
    ushort* Hm_b    = u + 14029824;   // 1280000
    ushort* emb_tcr_b = u + 15309824; // 25600000
    ushort* acc1_b  = u + 40909824;   // 25600000
    ushort* acc2_b  = u + 66509824;   // 25600000
    ushort* Ht_b    = u + 92109824;   // 25600000 -> ends 117709824 (~239 MB total)

    // ---------------- 1. merged prep ----------------
    prep_kernel<<<17591, 256, 0, stream>>>(
        ib,
        (const float4*)emb_tcr, (ushort4*)emb_tcr_b,
        (const float4*)emb_pep, (ushort4*)emb_pep_b,
        (const float4*)l1_mt_Wr, (ushort4*)Wr1_b,
        (const float4*)l2_mt_Wr, (ushort4*)Wr2_b,
        head_W1, (ushort4*)W1b_b, (ushort4*)W1c_b,
        l1_pm_Wl, l1_pm_Wr, l1_mt_Wl, Wcat1_b,
        l2_pm_Wl, l2_pm_Wr, l2_mt_Wl, Wcat2_b,
        (const float4*)emb_mhc, Acat1,
        proj_W, proj_b, Wcomp_b, bp);

    // ---------------- 2-6. CSR build ----------------
    hist2_kernel<<<(EPM + EMT + 255) / 256, 256, 0, stream>>>(dst_pm, dst_mt, deg_pm, deg_mt);
    blocksum2_kernel<<<103, 256, 0, stream>>>(deg_pm, deg_mt, bsum_pm, bsum_mt);
    scanb2_kernel<<<2, 128, 0, stream>>>(bsum_pm, bsum_mt);
    emit2_kernel<<<103, 256, 0, stream>>>(deg_pm, deg_mt, bsum_pm, bsum_mt,
                                          rp_pm, cnt_pm, rp_mt, cnt_mt);
    fill2_kernel<<<(EPM + EMT + 255) / 256, 256, 0, stream>>>(
        src_pm, dst_pm, src_mt, dst_mt, rp_pm, cur_pm, csr_pm, rp_mt, cur_mt, csr_mt);

    // ---------------- 7. pm gather + mean ----------------
    gatherpm_kernel<<<(NMHC + 7) / 8, 256, 0, stream>>>(rp_pm, csr_pm, emb_pep, Acat1, Acat2, NMHC);

    // ---------------- 8-11. mhc layers + mt gathers ----------------
    mfma_fused_kernel<256, 2, true, true><<<dim3((NMHC + 127) / 128, 4), 256, 0, stream>>>(
        NMHC, Acat1, Wcat1_b, l1_pm_bl, Acat2 + 128, 384, Zb);
    gatherb_kernel<<<(NTCR + 7) / 8, 256, 0, stream>>>(rp_mt, csr_mt, Zb, acc1_b, NTCR);
    mfma_fused_kernel<384, 2, true, true><<<dim3((NMHC + 127) / 128, 4), 256, 0, stream>>>(
        NMHC, Acat2, Wcat2_b, l2_pm_bl, mhc2_b, 256, Zb);
    gatherb_kernel<<<(NTCR + 7) / 8, 256, 0, stream>>>(rp_mt, csr_mt, Zb, acc2_b, NTCR);

    // ---------------- 12. mega tcr chain -> Ht ----------------
    tcr_mega_kernel<<<(NTCR + 63) / 64, 256, 0, stream>>>(
        NTCR, emb_tcr_b, Wr1_b, Wr2_b, W1c_b, l1_mt_bl, l2_mt_bl, cnt_mt,
        acc1_b, acc2_b, Ht_b);

    // ---------------- 13-14. Hp / Hm tables ----------------
    mfma_out_kernel<128, true><<<dim3((NPEP + 127) / 128, 2), 256, 0, stream>>>(
        NPEP, emb_pep_b, Wcomp_b, bp, Hp_b);
    mfma_out_kernel<256, false><<<dim3((NMHC + 127) / 128, 2), 256, 0, stream>>>(
        NMHC, mhc2_b, W1b_b, nullptr, Hm_b);

    // ---------------- 15. combine ----------------
    combine_kernel<<<(BB + 31) / 32, 256, 0, stream>>>(
        Hp_b, Hm_b, Ht_b, pack_pep, pack_mhc, pack_tcr,
        head_b1, head_W2, head_b2, out);
}

// Round 9
// 479.380 us; speedup vs baseline: 1.1116x; 1.1116x over previous
//
#include <hip/hip_runtime.h>

// ---------------- problem constants ----------------
constexpr int NPEP = 20000, NMHC = 5000, NTCR = 100000;
constexpr int EPM = 200000, EMT = 400000, BB = 50000;

typedef __attribute__((ext_vector_type(8))) short bf16x8;
typedef __attribute__((ext_vector_type(4))) float f32x4;

__device__ inline ushort f2bf(float x) {
    union { float f; unsigned u; } v; v.f = x;
    unsigned r = (v.u + 0x7FFF + ((v.u >> 16) & 1)) >> 16;
    return (ushort)r;
}
__device__ inline float bf2f(ushort b) {
    union { unsigned u; float f; } t; t.u = ((unsigned)b) << 16; return t.f;
}
__device__ inline void bf2x2(unsigned u, float& a, float& b) {
    union { unsigned x; float f; } t1, t2;
    t1.x = u << 16; t2.x = u & 0xffff0000u;
    a = t1.f; b = t2.f;
}
__device__ inline ushort4 f4bf(float4 v) {
    return make_ushort4(f2bf(v.x), f2bf(v.y), f2bf(v.z), f2bf(v.w));
}

// ---------------- merged prep kernel (block-range dispatch) ----------------
__global__ __launch_bounds__(256) void prep_kernel(
    int* __restrict__ ibz,
    const float4* __restrict__ emb_tcr, ushort4* __restrict__ emb_tcr_b,
    const float4* __restrict__ emb_pep, ushort4* __restrict__ emb_pep_b,
    const float4* __restrict__ Wr1f, ushort4* __restrict__ Wr1_b,
    const float4* __restrict__ Wr2f, ushort4* __restrict__ Wr2_b,
    const float* __restrict__ head_W1, ushort4* __restrict__ W1b_b, ushort4* __restrict__ W1c_b,
    const float* __restrict__ l1_pm_Wl, const float* __restrict__ l1_pm_Wr,
    const float* __restrict__ l1_mt_Wl, ushort* __restrict__ Wcat1_b,
    const float* __restrict__ l2_pm_Wl, const float* __restrict__ l2_pm_Wr,
    const float* __restrict__ l2_mt_Wl, ushort* __restrict__ Wcat2_b,
    const float4* __restrict__ emb_mhc, ushort* __restrict__ Acat1,
    const float* __restrict__ proj_W, const float* __restrict__ proj_b,
    ushort* __restrict__ Wcomp_b, float* __restrict__ bp) {
    __shared__ float red[128];
    const int b = blockIdx.x, tid = threadIdx.x;
    if (b < 206) {
        int i = b * 256 + tid;
        if (i < 52500) ((int4*)ibz)[i] = make_int4(0, 0, 0, 0);
    } else if (b < 12706) {
        int i = (b - 206) * 256 + tid;
        if (i < 3200000) emb_tcr_b[i] = f4bf(emb_tcr[i]);
    } else if (b < 15206) {
        int i = (b - 12706) * 256 + tid;
        if (i < 640000) emb_pep_b[i] = f4bf(emb_pep[i]);
    } else if (b < 15238) {
        int i = (b - 15206) * 256 + tid;
        if (i < 8192) Wr1_b[i] = f4bf(Wr1f[i]);
    } else if (b < 15302) {
        int i = (b - 15238) * 256 + tid;
        if (i < 16384) Wr2_b[i] = f4bf(Wr2f[i]);
    } else if (b < 15366) {
        int i = (b - 15302) * 256 + tid;
        if (i < 16384) {
            int n = i >> 6, k4 = (i & 63) * 4;
            float4 v = *(const float4*)(head_W1 + (size_t)n * 768 + 256 + k4);
            W1b_b[i] = f4bf(v);
        }
    } else if (b < 15430) {
        int i = (b - 15366) * 256 + tid;
        if (i < 16384) {
            int n = i >> 6, k4 = (i & 63) * 4;
            float4 v = *(const float4*)(head_W1 + (size_t)n * 768 + 512 + k4);
            W1c_b[i] = f4bf(v);
        }
    } else if (b < 15942) {
        int idx = (b - 15430) * 256 + tid;   // 512x256
        if (idx < 131072) {
            int r = idx >> 8, k = idx & 255;
            float v;
            if (r < 256) v = (k < 128) ? l1_pm_Wl[r * 128 + k] : l1_pm_Wr[r * 128 + (k - 128)];
            else         v = (k < 128) ? 0.f : l1_mt_Wl[(r - 256) * 128 + (k - 128)];
            Wcat1_b[idx] = f2bf(v);
        }
    } else if (b < 16710) {
        int idx = (b - 15942) * 256 + tid;   // 512x384
        if (idx < 196608) {
            int r = idx / 384, k = idx - r * 384;
            float v;
            if (r < 256) v = (k < 128) ? l2_pm_Wl[r * 128 + k] : l2_pm_Wr[r * 256 + (k - 128)];
            else         v = (k < 128) ? 0.f : l2_mt_Wl[(r - 256) * 256 + (k - 128)];
            Wcat2_b[idx] = f2bf(v);
        }
    } else if (b < 17335) {
        int i4 = (b - 16710) * 256 + tid;
        if (i4 < 160000) {
            int r = i4 >> 5, c4 = (i4 & 31) * 4;
            *(ushort4*)(Acat1 + (size_t)r * 256 + 128 + c4) = f4bf(emb_mhc[i4]);
        }
    } else {
        // wcomp: one block per output row i (0..255)
        int i = b - 17335;
        const float* w1row = head_W1 + (size_t)i * 768;
        if (tid < 128) {
            float acc = 0.f;
            for (int k = 0; k < 256; k++) acc += w1row[k] * proj_W[k * 128 + tid];
            Wcomp_b[i * 128 + tid] = f2bf(acc);
            float pb = w1row[2 * tid] * proj_b[2 * tid] + w1row[2 * tid + 1] * proj_b[2 * tid + 1];
            red[tid] = pb;
        }
        __syncthreads();
        if (tid < 64) { red[tid] += red[tid + 64]; }
        __syncthreads();
        if (tid < 32) { red[tid] += red[tid + 32]; }
        __syncthreads();
        if (tid == 0) {
            float s = 0.f;
            for (int j = 0; j < 32; j++) s += red[j];
            bp[i] = s;
        }
    }
}

// ---------------- merged histogram ----------------
__global__ void hist2_kernel(const int* __restrict__ dst_pm, const int* __restrict__ dst_mt,
                             int* __restrict__ deg_pm, int* __restrict__ deg_mt) {
    int t = blockIdx.x * blockDim.x + threadIdx.x;
    if (t < EPM) atomicAdd(&deg_pm[dst_pm[t]], 1);
    else if (t < EPM + EMT) atomicAdd(&deg_mt[dst_mt[t - EPM]], 1);
}

// ---------------- merged blocksum ----------------
__global__ __launch_bounds__(256) void blocksum2_kernel(const int* __restrict__ deg_pm,
                                                        const int* __restrict__ deg_mt,
                                                        int* __restrict__ bsum_pm,
                                                        int* __restrict__ bsum_mt) {
    __shared__ int red[256];
    const int tid = threadIdx.x;
    const int* deg; int n, bi; int* bsum;
    if (blockIdx.x < 5) { deg = deg_pm; n = NMHC; bi = blockIdx.x; bsum = bsum_pm; }
    else { deg = deg_mt; n = NTCR; bi = blockIdx.x - 5; bsum = bsum_mt; }
    const int base = bi * 1024;
    int s = 0;
#pragma unroll
    for (int j = 0; j < 4; j++) {
        int i = base + tid + j * 256;
        if (i < n) s += deg[i];
    }
    red[tid] = s;
    __syncthreads();
    for (int off = 128; off > 0; off >>= 1) {
        if (tid < off) red[tid] += red[tid + off];
        __syncthreads();
    }
    if (tid == 0) bsum[bi] = red[0];
}

// ---------------- merged scan of block sums ----------------
__global__ __launch_bounds__(128) void scanb2_kernel(int* __restrict__ bsum_pm,
                                                     int* __restrict__ bsum_mt) {
    __shared__ int s[128];
    const int tid = threadIdx.x;
    int* bsum = (blockIdx.x == 0) ? bsum_pm : bsum_mt;
    const int nb = (blockIdx.x == 0) ? 5 : 98;
    int v = (tid < nb) ? bsum[tid] : 0;
    s[tid] = v;
    __syncthreads();
    for (int off = 1; off < 128; off <<= 1) {
        int t = (tid >= off) ? s[tid - off] : 0;
        __syncthreads();
        s[tid] += t;
        __syncthreads();
    }
    if (tid < nb) bsum[tid] = (tid > 0) ? s[tid - 1] : 0;
    if (tid == 0) bsum[nb] = s[nb - 1];
}

// ---------------- merged emit ----------------
__global__ __launch_bounds__(256) void emit2_kernel(const int* __restrict__ deg_pm,
                                                    const int* __restrict__ deg_mt,
                                                    const int* __restrict__ bsum_pm,
                                                    const int* __restrict__ bsum_mt,
                                                    int* __restrict__ rp_pm, float* __restrict__ cnt_pm,
                                                    int* __restrict__ rp_mt, float* __restrict__ cnt_mt) {
    __shared__ int tsum[256];
    const int tid = threadIdx.x;
    const int* deg; const int* bsum; int* rp; float* cnt; int n, nb, bi;
    if (blockIdx.x < 5) { deg = deg_pm; bsum = bsum_pm; rp = rp_pm; cnt = cnt_pm; n = NMHC; nb = 5; bi = blockIdx.x; }
    else { deg = deg_mt; bsum = bsum_mt; rp = rp_mt; cnt = cnt_mt; n = NTCR; nb = 98; bi = blockIdx.x - 5; }
    const int i0 = bi * 1024 + tid * 4;
    int4 v = make_int4(0, 0, 0, 0);
    if (i0 + 3 < n) v = *(const int4*)(deg + i0);
    else if (i0 < n) {
        int t[4] = {0, 0, 0, 0};
        for (int j = 0; j < 4 && i0 + j < n; j++) t[j] = deg[i0 + j];
        v = make_int4(t[0], t[1], t[2], t[3]);
    }
    int s = v.x + v.y + v.z + v.w;
    tsum[tid] = s;
    __syncthreads();
    for (int off = 1; off < 256; off <<= 1) {
        int t = (tid >= off) ? tsum[tid - off] : 0;
        __syncthreads();
        tsum[tid] += t;
        __syncthreads();
    }
    int ex = ((tid > 0) ? tsum[tid - 1] : 0) + bsum[bi];
    if (i0 + 3 < n) {
        int r1 = ex + v.x, r2 = r1 + v.y, r3 = r2 + v.z;
        *(int4*)(rp + i0) = make_int4(ex, r1, r2, r3);
        *(float4*)(cnt + i0) = make_float4((float)v.x, (float)v.y, (float)v.z, (float)v.w);
    } else if (i0 < n) {
        int r = ex;
        int vv[4] = {v.x, v.y, v.z, v.w};
        for (int j = 0; j < 4 && i0 + j < n; j++) {
            rp[i0 + j] = r;
            cnt[i0 + j] = (float)vv[j];
            r += vv[j];
        }
    }
    if (bi == 0 && tid == 0) rp[n] = bsum[nb];
}

// ---------------- merged CSR fill ----------------
__global__ void fill2_kernel(const int* __restrict__ src_pm, const int* __restrict__ dst_pm,
                             const int* __restrict__ src_mt, const int* __restrict__ dst_mt,
                             const int* __restrict__ rp_pm, int* __restrict__ cur_pm, int* __restrict__ csr_pm,
                             const int* __restrict__ rp_mt, int* __restrict__ cur_mt, int* __restrict__ csr_mt) {
    int t = blockIdx.x * blockDim.x + threadIdx.x;
    if (t < EPM) {
        int d = dst_pm[t];
        int pos = atomicAdd(&cur_pm[d], 1);
        csr_pm[rp_pm[d] + pos] = src_pm[t];
    } else if (t < EPM + EMT) {
        int t2 = t - EPM;
        int d = dst_mt[t2];
        int pos = atomicAdd(&cur_mt[d], 1);
        csr_mt[rp_mt[d] + pos] = src_mt[t2];
    }
}

// ---------------- pm gather + mean -> bf16 ----------------
__global__ __launch_bounds__(256) void gatherpm_kernel(const int* __restrict__ rp,
                                                       const int* __restrict__ csr_src,
                                                       const float* __restrict__ X,
                                                       ushort* __restrict__ A1, ushort* __restrict__ A2,
                                                       int n) {
    const int tid = threadIdx.x;
    const int r = blockIdx.x * 8 + (tid >> 5);
    const int lane = tid & 31;
    if (r >= n) return;
    const int e0 = rp[r], e1 = rp[r + 1];
    float4 s = make_float4(0.f, 0.f, 0.f, 0.f);
    for (int e = e0; e < e1; e++) {
        const int sidx = csr_src[e];
        float4 v = ((const float4*)(X + (long)sidx * 128))[lane];
        s.x += v.x; s.y += v.y; s.z += v.z; s.w += v.w;
    }
    float sc = 1.f / fmaxf((float)(e1 - e0), 1.f);
    ushort4 o = make_ushort4(f2bf(s.x * sc), f2bf(s.y * sc), f2bf(s.z * sc), f2bf(s.w * sc));
    *(ushort4*)(A1 + (size_t)r * 256 + lane * 4) = o;
    *(ushort4*)(A2 + (size_t)r * 384 + lane * 4) = o;
}

// ---------------- merged dual bf16 pull gather (mt relation) ----------------
__global__ __launch_bounds__(256) void gatherb2_kernel(const int* __restrict__ rp,
                                                       const int* __restrict__ csr_src,
                                                       const ushort* __restrict__ Z1,
                                                       const ushort* __restrict__ Z2,
                                                       ushort* __restrict__ a1,
                                                       ushort* __restrict__ a2, int n) {
    const int tid = threadIdx.x;
    const int r = blockIdx.x * 8 + (tid >> 5);
    const int lane = tid & 31;
    if (r >= n) return;
    const int e0 = rp[r], e1 = rp[r + 1];
    float s1[8] = {}, s2[8] = {};
    for (int e = e0; e < e1; e++) {
        const int sidx = csr_src[e];
        uint4 u1 = *(const uint4*)(Z1 + (size_t)sidx * 256 + lane * 8);
        uint4 u2 = *(const uint4*)(Z2 + (size_t)sidx * 256 + lane * 8);
        float a, b;
        bf2x2(u1.x, a, b); s1[0] += a; s1[1] += b;
        bf2x2(u1.y, a, b); s1[2] += a; s1[3] += b;
        bf2x2(u1.z, a, b); s1[4] += a; s1[5] += b;
        bf2x2(u1.w, a, b); s1[6] += a; s1[7] += b;
        bf2x2(u2.x, a, b); s2[0] += a; s2[1] += b;
        bf2x2(u2.y, a, b); s2[2] += a; s2[3] += b;
        bf2x2(u2.z, a, b); s2[4] += a; s2[5] += b;
        bf2x2(u2.w, a, b); s2[6] += a; s2[7] += b;
    }
    uint4 w1, w2;
    w1.x = (unsigned)f2bf(s1[0]) | ((unsigned)f2bf(s1[1]) << 16);
    w1.y = (unsigned)f2bf(s1[2]) | ((unsigned)f2bf(s1[3]) << 16);
    w1.z = (unsigned)f2bf(s1[4]) | ((unsigned)f2bf(s1[5]) << 16);
    w1.w = (unsigned)f2bf(s1[6]) | ((unsigned)f2bf(s1[7]) << 16);
    w2.x = (unsigned)f2bf(s2[0]) | ((unsigned)f2bf(s2[1]) << 16);
    w2.y = (unsigned)f2bf(s2[2]) | ((unsigned)f2bf(s2[3]) << 16);
    w2.z = (unsigned)f2bf(s2[4]) | ((unsigned)f2bf(s2[5]) << 16);
    w2.w = (unsigned)f2bf(s2[6]) | ((unsigned)f2bf(s2[7]) << 16);
    *(uint4*)(a1 + (size_t)r * 256 + lane * 8) = w1;
    *(uint4*)(a2 + (size_t)r * 256 + lane * 8) = w2;
}

// ---------------- bf16 MFMA fused GEMM (layer1/layer2): dual bf16 outputs ----------------
template <int K, int NB0, bool RELU0, bool G2>
__global__ __launch_bounds__(256, 2) void mfma_fused_kernel(
    int M, const ushort* __restrict__ A, const ushort* __restrict__ W,
    const float* __restrict__ bias,
    ushort* __restrict__ out0, int s0, ushort* __restrict__ out1) {
    constexpr int RS = 40;
    __shared__ ushort Als[128 * RS];
    __shared__ ushort Wls[128 * RS];
    const int tid = threadIdx.x;
    const int m0 = blockIdx.x * 128, n0 = blockIdx.y * 128;
    const int lane = tid & 63, w = tid >> 6;
    const int wm = w >> 1, wn = w & 1;
    const int m16 = lane & 15, q = lane >> 4;

    f32x4 acc[4][4] = {};

    for (int k0 = 0; k0 < K; k0 += 32) {
        bf16x8 a_st[2], w_st[2];
#pragma unroll
        for (int r = 0; r < 2; r++) {
            int chunk = tid + r * 256;
            int row = chunk >> 2, off = (chunk & 3) * 8;
            int ga = min(m0 + row, M - 1);
            a_st[r] = *(const bf16x8*)(A + (size_t)ga * K + k0 + off);
            w_st[r] = *(const bf16x8*)(W + (size_t)(n0 + row) * K + k0 + off);
        }
        __syncthreads();
#pragma unroll
        for (int r = 0; r < 2; r++) {
            int chunk = tid + r * 256;
            int row = chunk >> 2, off = (chunk & 3) * 8;
            *(bf16x8*)(&Als[row * RS + off]) = a_st[r];
            *(bf16x8*)(&Wls[row * RS + off]) = w_st[r];
        }
        __syncthreads();
        bf16x8 af[4], bf[4];
#pragma unroll
        for (int t = 0; t < 4; t++) {
            af[t] = *(const bf16x8*)(&Als[(wm * 64 + t * 16 + m16) * RS + q * 8]);
            bf[t] = *(const bf16x8*)(&Wls[(wn * 64 + t * 16 + m16) * RS + q * 8]);
        }
#pragma unroll
        for (int mt = 0; mt < 4; mt++)
#pragma unroll
            for (int nt = 0; nt < 4; nt++)
                acc[mt][nt] = __builtin_amdgcn_mfma_f32_16x16x32_bf16(af[mt], bf[nt], acc[mt][nt], 0, 0, 0);
    }

    const bool g1 = G2 && ((int)blockIdx.y >= NB0);
#pragma unroll
    for (int mt = 0; mt < 4; mt++) {
#pragma unroll
        for (int i = 0; i < 4; i++) {
            int row = m0 + wm * 64 + mt * 16 + q * 4 + i;
            if (row >= M) continue;
#pragma unroll
            for (int nt = 0; nt < 4; nt++) {
                int col = n0 + wn * 64 + nt * 16 + m16;
                float v = acc[mt][nt][i];
                if (!g1) {
                    v += bias[col];
                    if (RELU0) v = fmaxf(v, 0.f);
                    out0[(size_t)row * s0 + col] = f2bf(v);
                } else {
                    out1[(size_t)row * 256 + (col - NB0 * 128)] = f2bf(v);
                }
            }
        }
    }
}

// ---------------- full-row bf16 MFMA GEMM (tcr1): 128 rows x 256 cols per block ----------------
// Cb = relu(A@W^T + bias + bf16acc/cnt); A read ONCE (no col-split).
template <int K>
__global__ __launch_bounds__(256, 2) void rowgemm_kernel(
    int M, const ushort* __restrict__ A, const ushort* __restrict__ W,
    const float* __restrict__ bias, const float* __restrict__ cnt,
    const ushort* __restrict__ accp, ushort* __restrict__ Cb) {
    constexpr int RS = 40;
    __shared__ ushort Als[128 * RS];   // 10.2 KB
    __shared__ ushort Wls[256 * RS];   // 20.5 KB
    const int tid = threadIdx.x;
    const int m0 = blockIdx.x * 128;
    const int lane = tid & 63, w = tid >> 6;
    const int wm = w >> 1, wn = w & 1;          // wave: rows wm*64, cols wn*128
    const int m16 = lane & 15, q = lane >> 4;

    f32x4 acc[4][8] = {};

    for (int k0 = 0; k0 < K; k0 += 32) {
        bf16x8 a_st[2], w_st[4];
#pragma unroll
        for (int r = 0; r < 2; r++) {
            int chunk = tid + r * 256;          // 512 chunks: 128 rows x 4
            int row = chunk >> 2, off = (chunk & 3) * 8;
            int ga = min(m0 + row, M - 1);
            a_st[r] = *(const bf16x8*)(A + (size_t)ga * K + k0 + off);
        }
#pragma unroll
        for (int r = 0; r < 4; r++) {
            int chunk = tid + r * 256;          // 1024 chunks: 256 N-rows x 4
            int row = chunk >> 2, off = (chunk & 3) * 8;
            w_st[r] = *(const bf16x8*)(W + (size_t)row * K + k0 + off);
        }
        __syncthreads();
#pragma unroll
        for (int r = 0; r < 2; r++) {
            int chunk = tid + r * 256;
            int row = chunk >> 2, off = (chunk & 3) * 8;
            *(bf16x8*)(&Als[row * RS + off]) = a_st[r];
        }
#pragma unroll
        for (int r = 0; r < 4; r++) {
            int chunk = tid + r * 256;
            int row = chunk >> 2, off = (chunk & 3) * 8;
            *(bf16x8*)(&Wls[row * RS + off]) = w_st[r];
        }
        __syncthreads();
        bf16x8 af[4], bf[8];
#pragma unroll
        for (int t = 0; t < 4; t++)
            af[t] = *(const bf16x8*)(&Als[(wm * 64 + t * 16 + m16) * RS + q * 8]);
#pragma unroll
        for (int t = 0; t < 8; t++)
            bf[t] = *(const bf16x8*)(&Wls[(wn * 128 + t * 16 + m16) * RS + q * 8]);
#pragma unroll
        for (int mt = 0; mt < 4; mt++)
#pragma unroll
            for (int nt = 0; nt < 8; nt++)
                acc[mt][nt] = __builtin_amdgcn_mfma_f32_16x16x32_bf16(af[mt], bf[nt], acc[mt][nt], 0, 0, 0);
    }

#pragma unroll
    for (int mt = 0; mt < 4; mt++) {
#pragma unroll
        for (int i = 0; i < 4; i++) {
            int row = m0 + wm * 64 + mt * 16 + q * 4 + i;
            if (row >= M) continue;
            float es = 1.f / fmaxf(cnt[row], 1.f);
#pragma unroll
            for (int nt = 0; nt < 8; nt++) {
                int col = wn * 128 + nt * 16 + m16;
                float v = acc[mt][nt][i] + bias[col] + bf2f(accp[(size_t)row * 256 + col]) * es;
                Cb[(size_t)row * 256 + col] = f2bf(fmaxf(v, 0.f));
            }
        }
    }
}

// ---------------- fused tcr2 + Ht: 64 rows per block, LDS-staged, T round-trip ----------------
// stage1: T = relu(T1@Wr2^T + bl2 + acc2/cnt)   (K=256, staged LDS GEMM)
// stage2: Ht = T@W1c^T                          (K=256, af from LDS T, bf from L2)
__global__ __launch_bounds__(256, 2) void tcr2ht_kernel(
    int M, const ushort* __restrict__ T1, const ushort* __restrict__ Wr2,
    const ushort* __restrict__ W1c,
    const float* __restrict__ bl2, const float* __restrict__ cnt,
    const ushort* __restrict__ acc2, ushort* __restrict__ Ht) {
    constexpr int RS = 40;
    constexpr int RS2 = 264;                 // T row stride: 2-way conflicts max on b128
    __shared__ ushort Als[64 * RS];          // 5.1 KB
    __shared__ ushort Wls[256 * RS];         // 20.5 KB
    __shared__ ushort T[64 * RS2];           // 33.8 KB  (total 59.4 KB)
    const int tid = threadIdx.x;
    const int m0 = blockIdx.x * 64;
    const int lane = tid & 63, w = tid >> 6; // wave w: cols w*64..w*64+63
    const int m16 = lane & 15, q = lane >> 4;

    // ---- stage 1: staged GEMM ----
    {
        f32x4 acc[4][4] = {};
        for (int k0 = 0; k0 < 256; k0 += 32) {
            bf16x8 a_st, w_st[4];
            {
                int row = tid >> 2, off = (tid & 3) * 8;     // 256 chunks: 64 rows x 4
                int ga = min(m0 + row, M - 1);
                a_st = *(const bf16x8*)(T1 + (size_t)ga * 256 + k0 + off);
            }
#pragma unroll
            for (int r = 0; r < 4; r++) {
                int chunk = tid + r * 256;                   // 1024: 256 N-rows x 4
                int row = chunk >> 2, off = (chunk & 3) * 8;
                w_st[r] = *(const bf16x8*)(Wr2 + (size_t)row * 256 + k0 + off);
            }
            __syncthreads();
            {
                int row = tid >> 2, off = (tid & 3) * 8;
                *(bf16x8*)(&Als[row * RS + off]) = a_st;
            }
#pragma unroll
            for (int r = 0; r < 4; r++) {
                int chunk = tid + r * 256;
                int row = chunk >> 2, off = (chunk & 3) * 8;
                *(bf16x8*)(&Wls[row * RS + off]) = w_st[r];
            }
            __syncthreads();
            bf16x8 af[4], bf[4];
#pragma unroll
            for (int t = 0; t < 4; t++) {
                af[t] = *(const bf16x8*)(&Als[(t * 16 + m16) * RS + q * 8]);
                bf[t] = *(const bf16x8*)(&Wls[(w * 64 + t * 16 + m16) * RS + q * 8]);
            }
#pragma unroll
            for (int mt = 0; mt < 4; mt++)
#pragma unroll
                for (int nt = 0; nt < 4; nt++)
                    acc[mt][nt] = __builtin_amdgcn_mfma_f32_16x16x32_bf16(af[mt], bf[nt], acc[mt][nt], 0, 0, 0);
        }
        // epilogue -> T in LDS (write ALL 64 rows; clamped rows hold valid dup data)
#pragma unroll
        for (int mt = 0; mt < 4; mt++)
#pragma unroll
            for (int i = 0; i < 4; i++) {
                int lr = mt * 16 + q * 4 + i;
                int rc = min(m0 + lr, M - 1);
                float es = 1.f / fmaxf(cnt[rc], 1.f);
#pragma unroll
                for (int nt = 0; nt < 4; nt++) {
                    int col = w * 64 + nt * 16 + m16;
                    float v = acc[mt][nt][i] + bl2[col] + bf2f(acc2[(size_t)rc * 256 + col]) * es;
                    T[lr * RS2 + col] = f2bf(fmaxf(v, 0.f));
                }
            }
    }
    __syncthreads();

    // ---- stage 2: Ht = T @ W1c^T ----
    {
        f32x4 acc[4][4] = {};
        for (int k0 = 0; k0 < 256; k0 += 32) {
            bf16x8 af[4], bf[4];
#pragma unroll
            for (int t = 0; t < 4; t++)
                af[t] = *(const bf16x8*)(&T[(t * 16 + m16) * RS2 + k0 + q * 8]);
#pragma unroll
            for (int t = 0; t < 4; t++) {
                int n = w * 64 + t * 16 + m16;
                bf[t] = *(const bf16x8*)(W1c + (size_t)n * 256 + k0 + q * 8);
            }
#pragma unroll
            for (int mt = 0; mt < 4; mt++)
#pragma unroll
                for (int nt = 0; nt < 4; nt++)
                    acc[mt][nt] = __builtin_amdgcn_mfma_f32_16x16x32_bf16(af[mt], bf[nt], acc[mt][nt], 0, 0, 0);
        }
#pragma unroll
        for (int mt = 0; mt < 4; mt++)
#pragma unroll
            for (int i = 0; i < 4; i++) {
                int row = m0 + mt * 16 + q * 4 + i;
                if (row >= M) continue;
#pragma unroll
                for (int nt = 0; nt < 4; nt++) {
                    int col = w * 64 + nt * 16 + m16;
                    Ht[(size_t)row * 256 + col] = f2bf(acc[mt][nt][i]);
                }
            }
    }
}

// ---------------- bf16 MFMA GEMM, bf16 output (Hp/Hm tables) ----------------
template <int K, bool HASB>
__global__ __launch_bounds__(256, 2) void mfma_out_kernel(
    int M, const ushort* __restrict__ A, const ushort* __restrict__ W,
    const float* __restrict__ bias, ushort* __restrict__ out) {
    constexpr int RS = 40;
    __shared__ ushort Als[128 * RS];
    __shared__ ushort Wls[128 * RS];
    const int tid = threadIdx.x;
    const int m0 = blockIdx.x * 128, n0 = blockIdx.y * 128;
    const int lane = tid & 63, w = tid >> 6;
    const int wm = w >> 1, wn = w & 1;
    const int m16 = lane & 15, q = lane >> 4;

    f32x4 acc[4][4] = {};

    for (int k0 = 0; k0 < K; k0 += 32) {
        bf16x8 a_st[2], w_st[2];
#pragma unroll
        for (int r = 0; r < 2; r++) {
            int chunk = tid + r * 256;
            int row = chunk >> 2, off = (chunk & 3) * 8;
            int ga = min(m0 + row, M - 1);
            a_st[r] = *(const bf16x8*)(A + (size_t)ga * K + k0 + off);
            w_st[r] = *(const bf16x8*)(W + (size_t)(n0 + row) * K + k0 + off);
        }
        __syncthreads();
#pragma unroll
        for (int r = 0; r < 2; r++) {
            int chunk = tid + r * 256;
            int row = chunk >> 2, off = (chunk & 3) * 8;
            *(bf16x8*)(&Als[row * RS + off]) = a_st[r];
            *(bf16x8*)(&Wls[row * RS + off]) = w_st[r];
        }
        __syncthreads();
        bf16x8 af[4], bf[4];
#pragma unroll
        for (int t = 0; t < 4; t++) {
            af[t] = *(const bf16x8*)(&Als[(wm * 64 + t * 16 + m16) * RS + q * 8]);
            bf[t] = *(const bf16x8*)(&Wls[(wn * 64 + t * 16 + m16) * RS + q * 8]);
        }
#pragma unroll
        for (int mt = 0; mt < 4; mt++)
#pragma unroll
            for (int nt = 0; nt < 4; nt++)
                acc[mt][nt] = __builtin_amdgcn_mfma_f32_16x16x32_bf16(af[mt], bf[nt], acc[mt][nt], 0, 0, 0);
    }

#pragma unroll
    for (int mt = 0; mt < 4; mt++) {
#pragma unroll
        for (int i = 0; i < 4; i++) {
            int row = m0 + wm * 64 + mt * 16 + q * 4 + i;
            if (row >= M) continue;
#pragma unroll
            for (int nt = 0; nt < 4; nt++) {
                int col = n0 + wn * 64 + nt * 16 + m16;
                float v = acc[mt][nt][i];
                if (HASB) v += bias[col];
                out[(size_t)row * 256 + col] = f2bf(v);
            }
        }
    }
}

// ---------------- combine: out[i] = relu(Hp[pp]+Hm[pm]+Ht[pt]+b1) . W2 + b2 ----------------
__global__ __launch_bounds__(256) void combine_kernel(
    const ushort* __restrict__ Hp, const ushort* __restrict__ Hm, const ushort* __restrict__ Ht,
    const int* __restrict__ pp, const int* __restrict__ pm, const int* __restrict__ pt,
    const float* __restrict__ b1, const float* __restrict__ W2, const float* __restrict__ b2,
    float* __restrict__ out) {
    const int tid = threadIdx.x;
    const int lane = tid & 63, w = tid >> 6;
    const int c = lane * 4;
    const float4 b1v = *(const float4*)(b1 + c);
    const float4 w2v = *(const float4*)(W2 + c);
    const float b2v = b2[0];
    const int base = blockIdx.x * 32 + w * 8;
#pragma unroll
    for (int t = 0; t < 8; t++) {
        int i = base + t;
        if (i >= BB) return;
        int ra = pp[i], rb = pm[i], rc = pt[i];
        ushort4 ua = *(const ushort4*)(Hp + (size_t)ra * 256 + c);
        ushort4 ub = *(const ushort4*)(Hm + (size_t)rb * 256 + c);
        ushort4 uc = *(const ushort4*)(Ht + (size_t)rc * 256 + c);
        float h0 = fmaxf(bf2f(ua.x) + bf2f(ub.x) + bf2f(uc.x) + b1v.x, 0.f);
        float h1 = fmaxf(bf2f(ua.y) + bf2f(ub.y) + bf2f(uc.y) + b1v.y, 0.f);
        float h2 = fmaxf(bf2f(ua.z) + bf2f(ub.z) + bf2f(uc.z) + b1v.z, 0.f);
        float h3 = fmaxf(bf2f(ua.w) + bf2f(ub.w) + bf2f(uc.w) + b1v.w, 0.f);
        float p = h0 * w2v.x + h1 * w2v.y + h2 * w2v.z + h3 * w2v.w;
#pragma unroll
        for (int off = 32; off > 0; off >>= 1) p += __shfl_down(p, off);
        if (lane == 0) out[i] = p + b2v;
    }
}

// ---------------- launch ----------------
extern "C" void kernel_launch(void* const* d_in, const int* in_sizes, int n_in,
                              void* d_out, int out_size, void* d_ws, size_t ws_size,
                              hipStream_t stream) {
    const float* emb_pep = (const float*)d_in[0];
    const float* emb_mhc = (const float*)d_in[1];
    const float* emb_tcr = (const float*)d_in[2];
    const int* src_pm = (const int*)d_in[3];
    const int* dst_pm = (const int*)d_in[4];
    const int* src_mt = (const int*)d_in[5];
    const int* dst_mt = (const int*)d_in[6];
    const int* pack_pep = (const int*)d_in[7];
    const int* pack_mhc = (const int*)d_in[8];
    const int* pack_tcr = (const int*)d_in[9];
    const float* l1_pm_Wl = (const float*)d_in[10];
    const float* l1_pm_bl = (const float*)d_in[11];
    const float* l1_pm_Wr = (const float*)d_in[12];
    const float* l1_mt_Wl = (const float*)d_in[13];
    const float* l1_mt_bl = (const float*)d_in[14];
    const float* l1_mt_Wr = (const float*)d_in[15];
    const float* l2_pm_Wl = (const float*)d_in[16];
    const float* l2_pm_bl = (const float*)d_in[17];
    const float* l2_pm_Wr = (const float*)d_in[18];
    const float* l2_mt_Wl = (const float*)d_in[19];
    const float* l2_mt_bl = (const float*)d_in[20];
    const float* l2_mt_Wr = (const float*)d_in[21];
    const float* proj_W = (const float*)d_in[22];
    const float* proj_b = (const float*)d_in[23];
    const float* head_W1 = (const float*)d_in[24];
    const float* head_b1 = (const float*)d_in[25];
    const float* head_W2 = (const float*)d_in[26];
    const float* head_b2 = (const float*)d_in[27];
    float* out = (float*)d_out;

    // ---------------- workspace layout ----------------
    int* ib = (int*)d_ws;
    int* deg_pm = ib;                 // 5000
    int* cur_pm = ib + 5000;          // 5000
    int* deg_mt = ib + 10000;         // 100000
    int* cur_mt = ib + 110000;        // 100000   [zero region: first 210000 ints]
    int* rp_pm  = ib + 210000;        // 5001 (pad 5008)
    int* rp_mt  = ib + 215008;        // 100001 (pad 100008)
    int* csr_pm = ib + 315016;        // 200000
    int* csr_mt = ib + 515016;        // 400000
    int* bsum_pm = ib + 915016;       // 160
    int* bsum_mt = ib + 915176;       // 160 -> pad 915344

    float* f = (float*)(ib + 915344);
    float* cnt_pm = f;                // 5000
    float* cnt_mt = f + 5000;         // 100000
    float* bp     = f + 105000;       // 256 (pad 105344)

    ushort* u = (ushort*)(f + 105344);
    ushort* Wcat1_b = u;              // 131072
    ushort* Wcat2_b = u + 131072;     // 196608
    ushort* W1b_b   = u + 327680;     // 65536
    ushort* W1c_b   = u + 393216;     // 65536
    ushort* Wcomp_b = u + 458752;     // 32768
    ushort* Wr1_b   = u + 491520;     // 32768
    ushort* Wr2_b   = u + 524288;     // 65536
    ushort* Acat1   = u + 589824;     // 1280000
    ushort* Acat2   = u + 1869824;    // 1920000
    ushort* Zb1     = u + 3789824;    // 1280000
    ushort* Zb2     = u + 5069824;    // 1280000
    ushort* mhc2_b  = u + 6349824;    // 1280000
    ushort* emb_pep_b = u + 7629824;  // 2560000
    ushort* Hp_b    = u + 10189824;   // 5120000
    ushort* Hm_b    = u + 15309824;   // 1280000
    ushort* emb_tcr_b = u + 16589824; // 12800000 (100000x128)
    ushort* acc1_b  = u + 29389824;   // 25600000
    ushort* tcr1_b  = u + 54989824;   // 25600000
    ushort* acc2_b  = u + 80589824;   // 25600000 -> ends 106189824 (~216 MB total)
    ushort* Ht_b    = emb_tcr_b;      // aliases emb_tcr_b+acc1_b (dead by tcr2ht)

    // ---------------- 1. merged prep ----------------
    prep_kernel<<<17591, 256, 0, stream>>>(
        ib,
        (const float4*)emb_tcr, (ushort4*)emb_tcr_b,
        (const float4*)emb_pep, (ushort4*)emb_pep_b,
        (const float4*)l1_mt_Wr, (ushort4*)Wr1_b,
        (const float4*)l2_mt_Wr, (ushort4*)Wr2_b,
        head_W1, (ushort4*)W1b_b, (ushort4*)W1c_b,
        l1_pm_Wl, l1_pm_Wr, l1_mt_Wl, Wcat1_b,
        l2_pm_Wl, l2_pm_Wr, l2_mt_Wl, Wcat2_b,
        (const float4*)emb_mhc, Acat1,
        proj_W, proj_b, Wcomp_b, bp);

    // ---------------- 2-6. CSR build ----------------
    hist2_kernel<<<(EPM + EMT + 255) / 256, 256, 0, stream>>>(dst_pm, dst_mt, deg_pm, deg_mt);
    blocksum2_kernel<<<103, 256, 0, stream>>>(deg_pm, deg_mt, bsum_pm, bsum_mt);
    scanb2_kernel<<<2, 128, 0, stream>>>(bsum_pm, bsum_mt);
    emit2_kernel<<<103, 256, 0, stream>>>(deg_pm, deg_mt, bsum_pm, bsum_mt,
                                          rp_pm, cnt_pm, rp_mt, cnt_mt);
    fill2_kernel<<<(EPM + EMT + 255) / 256, 256, 0, stream>>>(
        src_pm, dst_pm, src_mt, dst_mt, rp_pm, cur_pm, csr_pm, rp_mt, cur_mt, csr_mt);

    // ---------------- 7. pm gather + mean ----------------
    gatherpm_kernel<<<(NMHC + 7) / 8, 256, 0, stream>>>(rp_pm, csr_pm, emb_pep, Acat1, Acat2, NMHC);

    // ---------------- 8-9. mhc layers ----------------
    mfma_fused_kernel<256, 2, true, true><<<dim3((NMHC + 127) / 128, 4), 256, 0, stream>>>(
        NMHC, Acat1, Wcat1_b, l1_pm_bl, Acat2 + 128, 384, Zb1);
    mfma_fused_kernel<384, 2, true, true><<<dim3((NMHC + 127) / 128, 4), 256, 0, stream>>>(
        NMHC, Acat2, Wcat2_b, l2_pm_bl, mhc2_b, 256, Zb2);

    // ---------------- 10. merged dual mt gather ----------------
    gatherb2_kernel<<<(NTCR + 7) / 8, 256, 0, stream>>>(rp_mt, csr_mt, Zb1, Zb2, acc1_b, acc2_b, NTCR);

    // ---------------- 11. tcr1 (full-row GEMM) ----------------
    rowgemm_kernel<128><<<(NTCR + 127) / 128, 256, 0, stream>>>(
        NTCR, emb_tcr_b, Wr1_b, l1_mt_bl, cnt_mt, acc1_b, tcr1_b);

    // ---------------- 12. fused tcr2 + Ht ----------------
    tcr2ht_kernel<<<(NTCR + 63) / 64, 256, 0, stream>>>(
        NTCR, tcr1_b, Wr2_b, W1c_b, l2_mt_bl, cnt_mt, acc2_b, Ht_b);

    // ---------------- 13-14. Hp / Hm tables ----------------
    mfma_out_kernel<128, true><<<dim3((NPEP + 127) / 128, 2), 256, 0, stream>>>(
        NPEP, emb_pep_b, Wcomp_b, bp, Hp_b);
    mfma_out_kernel<256, false><<<dim3((NMHC + 127) / 128, 2), 256, 0, stream>>>(
        NMHC, mhc2_b, W1b_b, nullptr, Hm_b);

    // ---------------- 15. combine ----------------
    combine_kernel<<<(BB + 31) / 32, 256, 0, stream>>>(
        Hp_b, Hm_b, Ht_b, pack_pep, pack_mhc, pack_tcr,
        head_b1, head_W2, head_b2, out);
}